// Round 7
// baseline (501.275 us; speedup 1.0000x reference)
//
#include <hip/hip_runtime.h>

#define NSTEPS 20
#define ALPHA  0.9f
#define VTH    1.0f
#define GSOMA  0.3f
#define ISCALE 0.5f

#define NOR  21
#define NORN 42
#define NLN  56
#define NPN  42
#define NKC  2000
#define NKCP 2048   // padded KC width (zero-filled)
#define NOD  34

#define TPB  256
#define KPER 32     // KCs per lane: 64 * 32 = 2048 (padded)

// ===== pad kernel: zero-pad KC-side weights into ws =====
// ws layout (floats): [0,2048) kc_to_apl | [2048,4096) apl_to_kc | [4096,...) pn_to_kc rows [42][2048]
__global__ void pad_kernel(const float* __restrict__ pn_to_kc,
                           const float* __restrict__ kc_to_apl,
                           const float* __restrict__ apl_to_kc,
                           float* __restrict__ ws)
{
    const int total = (2 + NPN) * NKCP;
    for (int i = blockIdx.x * 256 + threadIdx.x; i < total; i += gridDim.x * 256) {
        const int r = i >> 11, c = i & (NKCP - 1);
        float v = 0.f;
        if (c < NKC) {
            if      (r == 0) v = kc_to_apl[c];
            else if (r == 1) v = apl_to_kc[c];
            else             v = pn_to_kc[(r - 2) * NKC + c];
        }
        ws[i] = v;
    }
}

// ===== main kernel: one wave = one batch row; no barriers in the time loop =====
__global__ __launch_bounds__(TPB, 2)
void snn_wave(const float* __restrict__ or_input,   // [B,21]
              const float* __restrict__ or_gains,   // [21]
              const float* __restrict__ mapping,    // [21,42]
              const float* __restrict__ orn_to_pn,  // [42,42]
              const float* __restrict__ orn_to_ln,  // [42,56]
              const float* __restrict__ ln_to_pn,   // [56,42]
              const float* __restrict__ wsbuf,      // padded KC weights
              const float* __restrict__ dec_w,      // [2000,34]
              const float* __restrict__ dec_b,      // [34]
              float* __restrict__ out,              // [B,34]
              int batch)
{
    // transposed, zero-padded small-net weights: row j (=lane) holds all o contiguous
    __shared__ float sOlT[64 * 44];   // [j=ln][o] stride 44 (176B, 16B-aligned)
    __shared__ float sOpT[64 * 44];   // [j=pn][o]
    __shared__ float sLpT[64 * 56];   // [j=pn][l] stride 56 (224B, 16B-aligned)
    __shared__ float sSpg[NOR];

    const int tid  = threadIdx.x;
    const int lane = tid & 63;
    const int wid  = tid >> 6;

    for (int i = tid; i < 64 * 44; i += TPB) {
        const int j = i / 44, o = i % 44;
        sOlT[i] = (j < NLN && o < NORN) ? orn_to_ln[o * NLN + j] : 0.f;
        sOpT[i] = (j < NPN && o < NORN) ? orn_to_pn[o * NPN + j] : 0.f;
    }
    for (int i = tid; i < 64 * 56; i += TPB) {
        const int j = i / 56, l = i % 56;
        sLpT[i] = (j < NPN) ? ln_to_pn[l * NPN + j] : 0.f;
    }
    if (tid < NOR) sSpg[tid] = log1pf(expf(or_gains[tid]));  // softplus
    __syncthreads();   // the only block-wide barrier

    const int row = blockIdx.x * 4 + wid;
    if (row >= batch) return;   // whole wave exits together

    // ---- per-lane ORN drive (ascending i, same order as reference) ----
    float drive = 0.f;
    if (lane < NORN) {
        const float* x = or_input + (long)row * NOR;
        for (int i = 0; i < NOR; ++i) drive += x[i] * sSpg[i] * mapping[i * NORN + lane];
        drive *= ISCALE;
    }

    const float* k2a = wsbuf;             // padded kc_to_apl
    const float* a2k = wsbuf + NKCP;      // padded apl_to_kc
    const float* pnT = wsbuf + 2 * NKCP;  // padded pn_to_kc rows
    const int kbase = lane * KPER;        // 0..2016, always in padded range

    // ---- KC per-lane state: 32 KCs (padded KCs have all-zero weights) ----
    float vd[KPER], va[KPER], cnt[KPER], wa2k[KPER], wk2a[KPER];
#pragma unroll
    for (int j = 0; j < KPER; ++j) { vd[j] = 0.f; va[j] = 0.f; cnt[j] = 0.f; }
    {
        const float4* A = (const float4*)(a2k + kbase);
        const float4* K = (const float4*)(k2a + kbase);
#pragma unroll
        for (int q = 0; q < KPER / 4; ++q) {
            float4 a = A[q], k = K[q];
            wa2k[4*q+0] = a.x; wa2k[4*q+1] = a.y; wa2k[4*q+2] = a.z; wa2k[4*q+3] = a.w;
            wk2a[4*q+0] = k.x; wk2a[4*q+1] = k.y; wk2a[4*q+2] = k.z; wk2a[4*q+3] = k.w;
        }
    }

    float v_orn = 0.f, v_ln = 0.f, v_pn = 0.f, apl = 0.f;
    const float* rowOl = sOlT + lane * 44;
    const float* rowOp = sOpT + lane * 44;
    const float* rowLp = sLpT + lane * 56;

    // ================= time loop: zero barriers =================
    for (int t = 0; t < NSTEPS; ++t) {
        // --- ORN LIF (lane = ORN index) ---
        float sOrnF = 0.f;
        if (lane < NORN) {
            v_orn = ALPHA * v_orn + drive;
            if (v_orn - VTH > 0.f) { sOrnF = 1.f; v_orn = 0.f; }
        }

        // --- dense LN input + PN excitation over o=0..41 (pads are exact zeros) ---
        float aln = 0.f, apn = 0.f;
#pragma unroll
        for (int ob = 0; ob < 44; ob += 4) {
            float4 wol = *(const float4*)(rowOl + ob);
            float4 wop = *(const float4*)(rowOp + ob);
            float s0 = __shfl(sOrnF, ob + 0);
            float s1 = __shfl(sOrnF, ob + 1);
            float s2 = __shfl(sOrnF, ob + 2);
            float s3 = __shfl(sOrnF, ob + 3);
            // ascending-o sequential accumulation; s in {0,1} -> terms exact
            aln += s0 * wol.x; aln += s1 * wol.y; aln += s2 * wol.z; aln += s3 * wol.w;
            apn += s0 * wop.x; apn += s1 * wop.y; apn += s2 * wop.z; apn += s3 * wop.w;
        }

        // --- LN LIF (lane = LN index) ---
        float slF = 0.f;
        if (lane < NLN) {
            v_ln = ALPHA * v_ln + aln;
            if (v_ln - VTH > 0.f) { slF = 1.f; v_ln = 0.f; }
        }

        // --- dense PN inhibition over l=0..55 ---
        float h = 0.f;
#pragma unroll
        for (int lb = 0; lb < 56; lb += 4) {
            float4 w = *(const float4*)(rowLp + lb);
            float s0 = __shfl(slF, lb + 0);
            float s1 = __shfl(slF, lb + 1);
            float s2 = __shfl(slF, lb + 2);
            float s3 = __shfl(slF, lb + 3);
            h += s0 * w.x; h += s1 * w.y; h += s2 * w.z; h += s3 * w.w;
        }

        // --- PN LIF (lane = PN index) ---
        bool sp = false;
        if (lane < NPN) {
            v_pn = ALPHA * v_pn + apn - h;
            sp = (v_pn - VTH) > 0.f;
            if (sp) v_pn = 0.f;
        }
        unsigned long long mPn = __ballot(sp);

        // --- KC dendrite decay + APL inhibition (same order as proven R1 path) ---
#pragma unroll
        for (int j = 0; j < KPER; ++j) vd[j] = ALPHA * vd[j] - apl * wa2k[j];

        // --- gather over spiking PNs (padded rows: no tail guards) ---
        while (mPn) {
            const int p = __builtin_ctzll(mPn); mPn &= mPn - 1;
            const float4* w = (const float4*)(pnT + (long)p * NKCP + kbase);
            float4 tmp[KPER / 4];
#pragma unroll
            for (int q = 0; q < KPER / 4; ++q) tmp[q] = w[q];   // all 8 loads in flight
#pragma unroll
            for (int q = 0; q < KPER / 4; ++q) {
                vd[4*q+0] += tmp[q].x; vd[4*q+1] += tmp[q].y;
                vd[4*q+2] += tmp[q].z; vd[4*q+3] += tmp[q].w;
            }
        }

        // --- KC soma, spike, count, APL (intra-wave butterfly only) ---
        float aplp = 0.f;
#pragma unroll
        for (int j = 0; j < KPER; ++j) {
            va[j] = ALPHA * va[j] + GSOMA * (vd[j] - va[j]);
            float s = (va[j] - VTH) > 0.f ? 1.f : 0.f;
            va[j] *= (1.f - s);
            cnt[j] += s;
            aplp += s * wk2a[j];
        }
#pragma unroll
        for (int off = 32; off > 0; off >>= 1) aplp += __shfl_xor(aplp, off, 64);
        apl = fmaxf(aplp, 0.f);   // relu; used in next step's decay
    }

    // ================= epilogue: logits = (cnt/20) @ dec_w + dec_b =================
    float acc[NOD];
#pragma unroll
    for (int o = 0; o < NOD; ++o) acc[o] = 0.f;
#pragma unroll
    for (int j = 0; j < KPER; ++j) {
        float r = cnt[j] / 20.0f;
        if (r != 0.f) {   // padded KCs always have cnt==0 -> never index dec_w OOB
            const float* wr = dec_w + (long)(kbase + j) * NOD;
#pragma unroll
            for (int o = 0; o < NOD; ++o) acc[o] += r * wr[o];
        }
    }
#pragma unroll
    for (int o = 0; o < NOD; ++o) {
        float v = acc[o];
#pragma unroll
        for (int off = 32; off > 0; off >>= 1) v += __shfl_xor(v, off, 64);
        acc[o] = v;
    }
    if (lane == 0) {
        float* orow = out + (long)row * NOD;
#pragma unroll
        for (int o = 0; o < NOD; ++o) orow[o] = acc[o] + dec_b[o];
    }
}

// ===================== Fallback: round-1 fused kernel (proven) =====================
__global__ __launch_bounds__(TPB)
void snn_fused(const float* __restrict__ or_input, const float* __restrict__ or_gains,
               const float* __restrict__ mapping, const float* __restrict__ orn_to_pn,
               const float* __restrict__ orn_to_ln, const float* __restrict__ ln_to_pn,
               const float* __restrict__ pn_to_kc, const float* __restrict__ kc_to_apl,
               const float* __restrict__ apl_to_kc, const float* __restrict__ dec_w,
               const float* __restrict__ dec_b, float* __restrict__ out)
{
    __shared__ float sW_ol[NORN * NLN];
    __shared__ float sW_op[NORN * NPN];
    __shared__ float sW_lp[NLN * NPN];
    __shared__ float sDrive[NORN];
    __shared__ float sSpg[NOR];
    __shared__ float sOrn[NORN];
    __shared__ float sLn[NLN];
    __shared__ float sApl;
    __shared__ float sRed[4];
    __shared__ float sRed2[4 * NOD];
    __shared__ unsigned long long sMask;

    const int tid = threadIdx.x;
    const int b   = blockIdx.x;

    for (int i = tid; i < NORN * NLN; i += TPB) sW_ol[i] = orn_to_ln[i];
    for (int i = tid; i < NORN * NPN; i += TPB) sW_op[i] = orn_to_pn[i];
    for (int i = tid; i < NLN * NPN;  i += TPB) sW_lp[i] = ln_to_pn[i];
    if (tid < NOR) sSpg[tid] = log1pf(expf(or_gains[tid]));
    if (tid == 0)  sApl = 0.f;
    __syncthreads();

    if (tid < NORN) {
        const float* x = or_input + (long)b * NOR;
        float d = 0.f;
        for (int i = 0; i < NOR; ++i) d += x[i] * sSpg[i] * mapping[i * NORN + tid];
        sDrive[tid] = d * ISCALE;
    }

    const int  kbase = tid * 8;
    const bool act   = (kbase < NKC);
    float vd[8], va[8], cnt[8], wa2k[8], wk2a[8];
#pragma unroll
    for (int j = 0; j < 8; ++j) {
        vd[j] = 0.f; va[j] = 0.f; cnt[j] = 0.f;
        wa2k[j] = act ? apl_to_kc[kbase + j] : 0.f;
        wk2a[j] = act ? kc_to_apl[kbase + j] : 0.f;
    }
    float v_orn = 0.f, v_ln = 0.f, v_pn = 0.f, v_pn_exc = 0.f;
    __syncthreads();

    for (int t = 0; t < NSTEPS; ++t) {
        if (tid < NORN) {
            v_orn = ALPHA * v_orn + sDrive[tid];
            float s = (v_orn - VTH) > 0.f ? 1.f : 0.f;
            v_orn *= (1.f - s);
            sOrn[tid] = s;
        }
        __syncthreads();
        if (tid < NLN) {
            float a = 0.f;
            for (int o = 0; o < NORN; ++o) a += sOrn[o] * sW_ol[o * NLN + tid];
            v_ln = ALPHA * v_ln + a;
            float s = (v_ln - VTH) > 0.f ? 1.f : 0.f;
            v_ln *= (1.f - s);
            sLn[tid] = s;
        } else if (tid >= 64 && tid < 64 + NPN) {
            const int j = tid - 64;
            float a = 0.f;
            for (int o = 0; o < NORN; ++o) a += sOrn[o] * sW_op[o * NPN + j];
            v_pn_exc = a;
        }
        __syncthreads();
        if (tid >= 64 && tid < 64 + NPN) {
            const int j = tid - 64;
            float inh = 0.f;
            for (int l = 0; l < NLN; ++l) inh += sLn[l] * sW_lp[l * NPN + j];
            v_pn = ALPHA * v_pn + v_pn_exc - inh;
            bool s = (v_pn - VTH) > 0.f;
            if (s) v_pn = 0.f;
            unsigned long long bal = __ballot(s);
            if (tid == 64) sMask = bal;
        }
        __syncthreads();
        {
            const float apl = sApl;
#pragma unroll
            for (int j = 0; j < 8; ++j) vd[j] = ALPHA * vd[j] - apl * wa2k[j];
            unsigned long long m = sMask;
            while (m) {
                const int p = __builtin_ctzll(m);
                m &= m - 1;
                if (act) {
                    const float4* w = (const float4*)(pn_to_kc + (long)p * NKC + kbase);
                    float4 w0 = w[0], w1 = w[1];
                    vd[0] += w0.x; vd[1] += w0.y; vd[2] += w0.z; vd[3] += w0.w;
                    vd[4] += w1.x; vd[5] += w1.y; vd[6] += w1.z; vd[7] += w1.w;
                }
            }
            float aplp = 0.f;
#pragma unroll
            for (int j = 0; j < 8; ++j) {
                va[j] = ALPHA * va[j] + GSOMA * (vd[j] - va[j]);
                float s = (va[j] - VTH) > 0.f ? 1.f : 0.f;
                va[j] *= (1.f - s);
                cnt[j] += s;
                aplp += s * wk2a[j];
            }
            for (int off = 32; off > 0; off >>= 1) aplp += __shfl_xor(aplp, off, 64);
            if ((tid & 63) == 0) sRed[tid >> 6] = aplp;
        }
        __syncthreads();
        if (tid == 0) {
            float a = sRed[0] + sRed[1] + sRed[2] + sRed[3];
            sApl = fmaxf(a, 0.f);
        }
    }

    float acc[NOD];
#pragma unroll
    for (int o = 0; o < NOD; ++o) acc[o] = 0.f;
    if (act) {
#pragma unroll
        for (int j = 0; j < 8; ++j) {
            float r = cnt[j] / 20.0f;
            if (r != 0.f) {
                const float* wr = dec_w + (long)(kbase + j) * NOD;
#pragma unroll
                for (int o = 0; o < NOD; ++o) acc[o] += r * wr[o];
            }
        }
    }
#pragma unroll
    for (int o = 0; o < NOD; ++o) {
        float v = acc[o];
        for (int off = 32; off > 0; off >>= 1) v += __shfl_xor(v, off, 64);
        if ((tid & 63) == 0) sRed2[(tid >> 6) * NOD + o] = v;
    }
    __syncthreads();
    if (tid < NOD) {
        float v = sRed2[tid] + sRed2[NOD + tid] + sRed2[2 * NOD + tid] +
                  sRed2[3 * NOD + tid] + dec_b[tid];
        out[(long)b * NOD + tid] = v;
    }
}

extern "C" void kernel_launch(void* const* d_in, const int* in_sizes, int n_in,
                              void* d_out, int out_size, void* d_ws, size_t ws_size,
                              hipStream_t stream) {
    (void)n_in; (void)out_size;
    const float* or_input  = (const float*)d_in[0];
    const float* or_gains  = (const float*)d_in[1];
    const float* mapping   = (const float*)d_in[2];
    const float* orn_to_pn = (const float*)d_in[3];
    const float* orn_to_ln = (const float*)d_in[4];
    const float* ln_to_pn  = (const float*)d_in[5];
    const float* pn_to_kc  = (const float*)d_in[6];
    const float* kc_to_apl = (const float*)d_in[7];
    const float* apl_to_kc = (const float*)d_in[8];
    const float* dec_w     = (const float*)d_in[9];
    const float* dec_b     = (const float*)d_in[10];
    float* out = (float*)d_out;

    const int batch = in_sizes[0] / NOR;  // 4096
    const size_t need = (size_t)(2 + NPN) * NKCP * sizeof(float);  // 360448 B

    if (ws_size >= need) {
        float* ws = (float*)d_ws;
        hipLaunchKernelGGL(pad_kernel, dim3(176), dim3(256), 0, stream,
                           pn_to_kc, kc_to_apl, apl_to_kc, ws);
        hipLaunchKernelGGL(snn_wave, dim3((batch + 3) / 4), dim3(TPB), 0, stream,
                           or_input, or_gains, mapping, orn_to_pn, orn_to_ln, ln_to_pn,
                           ws, dec_w, dec_b, out, batch);
    } else {
        hipLaunchKernelGGL(snn_fused, dim3(batch), dim3(TPB), 0, stream,
                           or_input, or_gains, mapping, orn_to_pn, orn_to_ln,
                           ln_to_pn, pn_to_kc, kc_to_apl, apl_to_kc, dec_w, dec_b, out);
    }
}

// Round 8
// 336.659 us; speedup vs baseline: 1.4890x; 1.4890x over previous
//
#include <hip/hip_runtime.h>

#define NSTEPS 20
#define ALPHA  0.9f
#define VTH    1.0f
#define GSOMA  0.3f
#define ISCALE 0.5f

#define NOR  21
#define NORN 42
#define NLN  56
#define NPN  42
#define NKC  2000
#define NOD  34

#define TPB  256
#define KPER 8   // KCs per consumer thread: 250 * 8 = 2000

// ===================== Phase 1: small net -> PN spike masks =====================
// One wave per batch row. All three weight matrices live in REGISTERS
// (lane j holds column j of each). The time loop is pure VALU + shfl —
// zero memory traffic except the per-step 8B mask store. Accumulation is
// dense, sequential, ascending index: bit-identical to the proven R1 order
// (spikes are {0,1} so every term is exact).
__global__ __launch_bounds__(64, 2)
void phase1_reg(const float* __restrict__ or_input,   // [B,21]
                const float* __restrict__ or_gains,   // [21]
                const float* __restrict__ mapping,    // [21,42]
                const float* __restrict__ orn_to_pn,  // [42,42]
                const float* __restrict__ orn_to_ln,  // [42,56]
                const float* __restrict__ ln_to_pn,   // [56,42]
                unsigned long long* __restrict__ g_masks, // [B,20]
                int batch)
{
    const int lane = threadIdx.x;   // 0..63
    const int row  = blockIdx.x;
    if (row >= batch) return;

    const int jl = lane < NLN ? lane : 0;   // clamped column for safe loads
    const int jp = lane < NPN ? lane : 0;

    // per-lane weight columns (coalesced per-o loads; one-time, L2-hot)
    float wOl[NORN], wOp[NORN], wLp[NLN];
#pragma unroll
    for (int o = 0; o < NORN; ++o) {
        wOl[o] = orn_to_ln[o * NLN + jl];
        wOp[o] = orn_to_pn[o * NPN + jp];
    }
#pragma unroll
    for (int l = 0; l < NLN; ++l) wLp[l] = ln_to_pn[l * NPN + jp];

    // softplus(or_gains) in lanes 0..20, broadcast via shfl
    float spg = 0.f;
    if (lane < NOR) spg = log1pf(expf(or_gains[lane]));

    // drive_lane = I_SCALE * sum_i x[i]*spg[i]*mapping[i][lane]  (ascending i)
    float drive = 0.f;
    {
        const float* x = or_input + (long)row * NOR;
        const int jo = lane < NORN ? lane : 0;
#pragma unroll
        for (int i = 0; i < NOR; ++i) {
            float g = __shfl(spg, i);
            drive += x[i] * g * mapping[i * NORN + jo];
        }
        drive *= ISCALE;
    }

    float v_orn = 0.f, v_ln = 0.f, v_pn = 0.f;
    unsigned long long* outm = g_masks + (long)row * NSTEPS;

    for (int t = 0; t < NSTEPS; ++t) {
        // --- ORN LIF (lane = ORN index) ---
        float so = 0.f;
        if (lane < NORN) {
            v_orn = ALPHA * v_orn + drive;
            if (v_orn - VTH > 0.f) { so = 1.f; v_orn = 0.f; }
        }

        // --- dense LN input + PN excitation (shared spike broadcast) ---
        float aln = 0.f, apn = 0.f;
#pragma unroll
        for (int o = 0; o < NORN; ++o) {
            float s = __shfl(so, o);     // compile-time lane index
            aln += s * wOl[o];
            apn += s * wOp[o];
        }

        // --- LN LIF (lane = LN index) ---
        float sl = 0.f;
        if (lane < NLN) {
            v_ln = ALPHA * v_ln + aln;
            if (v_ln - VTH > 0.f) { sl = 1.f; v_ln = 0.f; }
        }

        // --- dense PN inhibition ---
        float h = 0.f;
#pragma unroll
        for (int l = 0; l < NLN; ++l) {
            float s = __shfl(sl, l);
            h += s * wLp[l];
        }

        // --- PN LIF (lane = PN index) ---
        bool sp = false;
        if (lane < NPN) {
            v_pn = ALPHA * v_pn + apn - h;
            sp = (v_pn - VTH) > 0.f;
            if (sp) v_pn = 0.f;
        }
        const unsigned long long mPn = __ballot(sp);
        if (lane == 0) outm[t] = mPn;
    }
}

// ===================== Phase 2: KC two-compartment + APL + logits =====================
// (R5 version, proven 90 us / absmax 0.0 — unchanged)
__global__ __launch_bounds__(TPB)
void phase2_kernel(const unsigned long long* __restrict__ g_masks, // [B,20]
                   const float* __restrict__ pn_to_kc,  // [42,2000]
                   const float* __restrict__ kc_to_apl, // [2000,1]
                   const float* __restrict__ apl_to_kc, // [1,2000]
                   const float* __restrict__ dec_w,     // [2000,34]
                   const float* __restrict__ dec_b,     // [34]
                   float* __restrict__ out)             // [B,34]
{
    __shared__ float sRed[2][4];
    __shared__ float sRed2[4 * NOD];

    const int tid  = threadIdx.x;
    const int lane = tid & 63;
    const int wid  = tid >> 6;
    const int b    = blockIdx.x;

    const int  kbase = tid * KPER;
    const bool act   = (kbase < NKC);   // tid < 250
    float vd[KPER], va[KPER], cnt[KPER], wa2k[KPER], wk2a[KPER];
#pragma unroll
    for (int j = 0; j < KPER; ++j) { vd[j] = 0.f; va[j] = 0.f; cnt[j] = 0.f; }
    {
        const float4* a4 = (const float4*)(apl_to_kc + (act ? kbase : 0));
        const float4* k4 = (const float4*)(kc_to_apl + (act ? kbase : 0));
        float4 a0 = a4[0], a1 = a4[1], k0 = k4[0], k1 = k4[1];
        const float g = act ? 1.f : 0.f;
        wa2k[0] = g * a0.x; wa2k[1] = g * a0.y; wa2k[2] = g * a0.z; wa2k[3] = g * a0.w;
        wa2k[4] = g * a1.x; wa2k[5] = g * a1.y; wa2k[6] = g * a1.z; wa2k[7] = g * a1.w;
        wk2a[0] = g * k0.x; wk2a[1] = g * k0.y; wk2a[2] = g * k0.z; wk2a[3] = g * k0.w;
        wk2a[4] = g * k1.x; wk2a[5] = g * k1.y; wk2a[6] = g * k1.z; wk2a[7] = g * k1.w;
    }
    if (tid < 8) sRed[tid >> 2][tid & 3] = 0.f;   // zero both buffers
    __syncthreads();

    const unsigned long long* gm = g_masks + (long)b * NSTEPS;

    for (int t = 0; t < NSTEPS; ++t) {
        const float* rp = sRed[(t + 1) & 1];
        const float apl = fmaxf(rp[0] + rp[1] + rp[2] + rp[3], 0.f);

#pragma unroll
        for (int j = 0; j < KPER; ++j) vd[j] = ALPHA * vd[j] - apl * wa2k[j];

        unsigned long long m = gm[t];   // wave-uniform scalar load
        while (m) {
            const int p0 = __builtin_ctzll(m); m &= m - 1;
            int p1 = p0; float f1 = 0.f;
            if (m) { p1 = __builtin_ctzll(m); m &= m - 1; f1 = 1.f; }
            if (act) {
                const float4* w0 = (const float4*)(pn_to_kc + (long)p0 * NKC + kbase);
                const float4* w1 = (const float4*)(pn_to_kc + (long)p1 * NKC + kbase);
                float4 a0 = w0[0], a1 = w0[1];
                float4 b0 = w1[0], b1 = w1[1];
                vd[0] += a0.x; vd[1] += a0.y; vd[2] += a0.z; vd[3] += a0.w;
                vd[4] += a1.x; vd[5] += a1.y; vd[6] += a1.z; vd[7] += a1.w;
                vd[0] += f1 * b0.x; vd[1] += f1 * b0.y; vd[2] += f1 * b0.z; vd[3] += f1 * b0.w;
                vd[4] += f1 * b1.x; vd[5] += f1 * b1.y; vd[6] += f1 * b1.z; vd[7] += f1 * b1.w;
            }
        }

        float aplp = 0.f;
#pragma unroll
        for (int j = 0; j < KPER; ++j) {
            va[j] = ALPHA * va[j] + GSOMA * (vd[j] - va[j]);
            float s = (va[j] - VTH) > 0.f ? 1.f : 0.f;
            va[j] *= (1.f - s);
            cnt[j] += s;
            aplp += s * wk2a[j];
        }
        for (int off = 32; off > 0; off >>= 1) aplp += __shfl_xor(aplp, off, 64);
        if (lane == 0) sRed[t & 1][wid] = aplp;
        __syncthreads();
    }

    float acc[NOD];
#pragma unroll
    for (int o = 0; o < NOD; ++o) acc[o] = 0.f;
    if (act) {
#pragma unroll
        for (int j = 0; j < KPER; ++j) {
            float r = cnt[j] / 20.0f;
            if (r != 0.f) {
                const float* wr = dec_w + (long)(kbase + j) * NOD;
#pragma unroll
                for (int o = 0; o < NOD; ++o) acc[o] += r * wr[o];
            }
        }
    }
#pragma unroll
    for (int o = 0; o < NOD; ++o) {
        float v = acc[o];
        for (int off = 32; off > 0; off >>= 1) v += __shfl_xor(v, off, 64);
        if (lane == 0) sRed2[wid * NOD + o] = v;
    }
    __syncthreads();
    if (tid < NOD) {
        float v = sRed2[tid] + sRed2[NOD + tid] + sRed2[2 * NOD + tid] +
                  sRed2[3 * NOD + tid] + dec_b[tid];
        out[(long)b * NOD + tid] = v;
    }
}

// ===================== Fallback: round-1 fused kernel (proven) =====================
__global__ __launch_bounds__(TPB)
void snn_fused(const float* __restrict__ or_input, const float* __restrict__ or_gains,
               const float* __restrict__ mapping, const float* __restrict__ orn_to_pn,
               const float* __restrict__ orn_to_ln, const float* __restrict__ ln_to_pn,
               const float* __restrict__ pn_to_kc, const float* __restrict__ kc_to_apl,
               const float* __restrict__ apl_to_kc, const float* __restrict__ dec_w,
               const float* __restrict__ dec_b, float* __restrict__ out)
{
    __shared__ float sW_ol[NORN * NLN];
    __shared__ float sW_op[NORN * NPN];
    __shared__ float sW_lp[NLN * NPN];
    __shared__ float sDrive[NORN];
    __shared__ float sSpg[NOR];
    __shared__ float sOrn[NORN];
    __shared__ float sLn[NLN];
    __shared__ float sApl;
    __shared__ float sRed[4];
    __shared__ float sRed2[4 * NOD];
    __shared__ unsigned long long sMask;

    const int tid = threadIdx.x;
    const int b   = blockIdx.x;

    for (int i = tid; i < NORN * NLN; i += TPB) sW_ol[i] = orn_to_ln[i];
    for (int i = tid; i < NORN * NPN; i += TPB) sW_op[i] = orn_to_pn[i];
    for (int i = tid; i < NLN * NPN;  i += TPB) sW_lp[i] = ln_to_pn[i];
    if (tid < NOR) sSpg[tid] = log1pf(expf(or_gains[tid]));
    if (tid == 0)  sApl = 0.f;
    __syncthreads();

    if (tid < NORN) {
        const float* x = or_input + (long)b * NOR;
        float d = 0.f;
        for (int i = 0; i < NOR; ++i) d += x[i] * sSpg[i] * mapping[i * NORN + tid];
        sDrive[tid] = d * ISCALE;
    }

    const int  kbase = tid * KPER;
    const bool act   = (kbase < NKC);
    float vd[KPER], va[KPER], cnt[KPER], wa2k[KPER], wk2a[KPER];
#pragma unroll
    for (int j = 0; j < KPER; ++j) {
        vd[j] = 0.f; va[j] = 0.f; cnt[j] = 0.f;
        wa2k[j] = act ? apl_to_kc[kbase + j] : 0.f;
        wk2a[j] = act ? kc_to_apl[kbase + j] : 0.f;
    }
    float v_orn = 0.f, v_ln = 0.f, v_pn = 0.f, v_pn_exc = 0.f;
    __syncthreads();

    for (int t = 0; t < NSTEPS; ++t) {
        if (tid < NORN) {
            v_orn = ALPHA * v_orn + sDrive[tid];
            float s = (v_orn - VTH) > 0.f ? 1.f : 0.f;
            v_orn *= (1.f - s);
            sOrn[tid] = s;
        }
        __syncthreads();
        if (tid < NLN) {
            float a = 0.f;
            for (int o = 0; o < NORN; ++o) a += sOrn[o] * sW_ol[o * NLN + tid];
            v_ln = ALPHA * v_ln + a;
            float s = (v_ln - VTH) > 0.f ? 1.f : 0.f;
            v_ln *= (1.f - s);
            sLn[tid] = s;
        } else if (tid >= 64 && tid < 64 + NPN) {
            const int j = tid - 64;
            float a = 0.f;
            for (int o = 0; o < NORN; ++o) a += sOrn[o] * sW_op[o * NPN + j];
            v_pn_exc = a;
        }
        __syncthreads();
        if (tid >= 64 && tid < 64 + NPN) {
            const int j = tid - 64;
            float inh = 0.f;
            for (int l = 0; l < NLN; ++l) inh += sLn[l] * sW_lp[l * NPN + j];
            v_pn = ALPHA * v_pn + v_pn_exc - inh;
            bool s = (v_pn - VTH) > 0.f;
            if (s) v_pn = 0.f;
            unsigned long long bal = __ballot(s);
            if (tid == 64) sMask = bal;
        }
        __syncthreads();
        {
            const float apl = sApl;
#pragma unroll
            for (int j = 0; j < KPER; ++j) vd[j] = ALPHA * vd[j] - apl * wa2k[j];
            unsigned long long m = sMask;
            while (m) {
                const int p = __builtin_ctzll(m);
                m &= m - 1;
                if (act) {
                    const float4* w = (const float4*)(pn_to_kc + (long)p * NKC + kbase);
                    float4 w0 = w[0], w1 = w[1];
                    vd[0] += w0.x; vd[1] += w0.y; vd[2] += w0.z; vd[3] += w0.w;
                    vd[4] += w1.x; vd[5] += w1.y; vd[6] += w1.z; vd[7] += w1.w;
                }
            }
            float aplp = 0.f;
#pragma unroll
            for (int j = 0; j < KPER; ++j) {
                va[j] = ALPHA * va[j] + GSOMA * (vd[j] - va[j]);
                float s = (va[j] - VTH) > 0.f ? 1.f : 0.f;
                va[j] *= (1.f - s);
                cnt[j] += s;
                aplp += s * wk2a[j];
            }
            for (int off = 32; off > 0; off >>= 1) aplp += __shfl_xor(aplp, off, 64);
            if ((tid & 63) == 0) sRed[tid >> 6] = aplp;
        }
        __syncthreads();
        if (tid == 0) {
            float a = sRed[0] + sRed[1] + sRed[2] + sRed[3];
            sApl = fmaxf(a, 0.f);
        }
    }

    float acc[NOD];
#pragma unroll
    for (int o = 0; o < NOD; ++o) acc[o] = 0.f;
    if (act) {
#pragma unroll
        for (int j = 0; j < KPER; ++j) {
            float r = cnt[j] / 20.0f;
            if (r != 0.f) {
                const float* wr = dec_w + (long)(kbase + j) * NOD;
#pragma unroll
                for (int o = 0; o < NOD; ++o) acc[o] += r * wr[o];
            }
        }
    }
#pragma unroll
    for (int o = 0; o < NOD; ++o) {
        float v = acc[o];
        for (int off = 32; off > 0; off >>= 1) v += __shfl_xor(v, off, 64);
        if ((tid & 63) == 0) sRed2[(tid >> 6) * NOD + o] = v;
    }
    __syncthreads();
    if (tid < NOD) {
        float v = sRed2[tid] + sRed2[NOD + tid] + sRed2[2 * NOD + tid] +
                  sRed2[3 * NOD + tid] + dec_b[tid];
        out[(long)b * NOD + tid] = v;
    }
}

extern "C" void kernel_launch(void* const* d_in, const int* in_sizes, int n_in,
                              void* d_out, int out_size, void* d_ws, size_t ws_size,
                              hipStream_t stream) {
    (void)n_in; (void)out_size;
    const float* or_input  = (const float*)d_in[0];
    const float* or_gains  = (const float*)d_in[1];
    const float* mapping   = (const float*)d_in[2];
    const float* orn_to_pn = (const float*)d_in[3];
    const float* orn_to_ln = (const float*)d_in[4];
    const float* ln_to_pn  = (const float*)d_in[5];
    const float* pn_to_kc  = (const float*)d_in[6];
    const float* kc_to_apl = (const float*)d_in[7];
    const float* apl_to_kc = (const float*)d_in[8];
    const float* dec_w     = (const float*)d_in[9];
    const float* dec_b     = (const float*)d_in[10];
    float* out = (float*)d_out;

    const int batch = in_sizes[0] / NOR;  // 4096
    const size_t need = (size_t)batch * NSTEPS * sizeof(unsigned long long);

    if (ws_size >= need) {
        unsigned long long* g_masks = (unsigned long long*)d_ws;
        hipLaunchKernelGGL(phase1_reg, dim3(batch), dim3(64), 0, stream,
                           or_input, or_gains, mapping, orn_to_pn, orn_to_ln, ln_to_pn,
                           g_masks, batch);
        hipLaunchKernelGGL(phase2_kernel, dim3(batch), dim3(TPB), 0, stream,
                           g_masks, pn_to_kc, kc_to_apl, apl_to_kc, dec_w, dec_b, out);
    } else {
        hipLaunchKernelGGL(snn_fused, dim3(batch), dim3(TPB), 0, stream,
                           or_input, or_gains, mapping, orn_to_pn, orn_to_ln,
                           ln_to_pn, pn_to_kc, kc_to_apl, apl_to_kc, dec_w, dec_b, out);
    }
}

// Round 9
// 210.719 us; speedup vs baseline: 2.3789x; 1.5977x over previous
//
#include <hip/hip_runtime.h>

#define NSTEPS 20
#define ALPHA  0.9f
#define VTH    1.0f
#define GSOMA  0.3f
#define ISCALE 0.5f

#define NOR  21
#define NORN 42
#define NLN  56
#define NPN  42
#define NKC  2000
#define NOD  34

#define TPB  256
#define KPER 8   // KCs per consumer thread: 250 * 8 = 2000

// ============ Phase 1a: ORN + LN dynamics -> {mOrn, mLn} per step ============
// One wave per row. Only wOl[42] in registers (~60 VGPR total, no spill).
// Zero LDS, zero barriers. Skipping zero spike terms is exact (acc >= 0).
__global__ __launch_bounds__(64)
void phase1a(const float* __restrict__ or_input,   // [B,21]
             const float* __restrict__ or_gains,   // [21]
             const float* __restrict__ mapping,    // [21,42]
             const float* __restrict__ orn_to_ln,  // [42,56]
             ulonglong2* __restrict__ gAB,         // [B,20] {mOrn, mLn}
             int batch)
{
    const int lane = threadIdx.x;
    const int row  = blockIdx.x;
    if (row >= batch) return;

    const int jl = lane < NLN ? lane : 0;
    float wOl[NORN];
#pragma unroll
    for (int o = 0; o < NORN; ++o) wOl[o] = orn_to_ln[o * NLN + jl];

    float spg = 0.f;
    if (lane < NOR) spg = log1pf(expf(or_gains[lane]));  // softplus

    float drive = 0.f;
    {
        const float* x = or_input + (long)row * NOR;
        const int jo = lane < NORN ? lane : 0;
#pragma unroll
        for (int i = 0; i < NOR; ++i) {
            float g = __shfl(spg, i);
            drive += x[i] * g * mapping[i * NORN + jo];
        }
        drive *= ISCALE;
    }

    float v_orn = 0.f, v_ln = 0.f;
    ulonglong2* outm = gAB + (long)row * NSTEPS;

    for (int t = 0; t < NSTEPS; ++t) {
        // ORN LIF (lane = ORN index)
        bool so = false;
        if (lane < NORN) {
            v_orn = ALPHA * v_orn + drive;
            so = (v_orn - VTH) > 0.f;
            if (so) v_orn = 0.f;
        }
        const unsigned long long mOrn = __ballot(so);
        const unsigned int mo_lo = (unsigned int)mOrn;
        const unsigned int mo_hi = (unsigned int)(mOrn >> 32);

        // LN input: dense ascending-o; s in {0,1} via bit extract (exact)
        float aln = 0.f;
#pragma unroll
        for (int o = 0; o < 32; ++o) aln += (float)((mo_lo >> o) & 1u) * wOl[o];
#pragma unroll
        for (int o = 32; o < NORN; ++o) aln += (float)((mo_hi >> (o - 32)) & 1u) * wOl[o];

        bool sl = false;
        if (lane < NLN) {
            v_ln = ALPHA * v_ln + aln;
            sl = (v_ln - VTH) > 0.f;
            if (sl) v_ln = 0.f;
        }
        const unsigned long long mLn = __ballot(sl);
        if (lane == 0) outm[t] = make_ulonglong2(mOrn, mLn);
    }
}

// ============ Phase 1b: PN dynamics -> PN spike masks ============
// One wave per row. wOp[42]+wLp[56] = 98 weight regs + ~20 temps < 128: no spill.
__global__ __launch_bounds__(64)
void phase1b(const float* __restrict__ orn_to_pn,  // [42,42]
             const float* __restrict__ ln_to_pn,   // [56,42]
             const ulonglong2* __restrict__ gAB,   // [B,20]
             unsigned long long* __restrict__ gPN, // [B,20]
             int batch)
{
    const int lane = threadIdx.x;
    const int row  = blockIdx.x;
    if (row >= batch) return;

    const int jp = lane < NPN ? lane : 0;
    float wOp[NORN], wLp[NLN];
#pragma unroll
    for (int o = 0; o < NORN; ++o) wOp[o] = orn_to_pn[o * NPN + jp];
#pragma unroll
    for (int l = 0; l < NLN; ++l) wLp[l] = ln_to_pn[l * NPN + jp];

    const ulonglong2* inm = gAB + (long)row * NSTEPS;
    unsigned long long* outm = gPN + (long)row * NSTEPS;

    float v_pn = 0.f;
    ulonglong2 ab = inm[0];   // prefetch t=0

    for (int t = 0; t < NSTEPS; ++t) {
        ulonglong2 abn;
        if (t < NSTEPS - 1) abn = inm[t + 1];   // prefetch next step

        const unsigned int mo_lo = (unsigned int)ab.x;
        const unsigned int mo_hi = (unsigned int)(ab.x >> 32);
        const unsigned int ml_lo = (unsigned int)ab.y;
        const unsigned int ml_hi = (unsigned int)(ab.y >> 32);

        // PN excitation: dense ascending-o (exact: s in {0,1})
        float apn = 0.f;
#pragma unroll
        for (int o = 0; o < 32; ++o) apn += (float)((mo_lo >> o) & 1u) * wOp[o];
#pragma unroll
        for (int o = 32; o < NORN; ++o) apn += (float)((mo_hi >> (o - 32)) & 1u) * wOp[o];

        // PN inhibition: dense ascending-l
        float h = 0.f;
#pragma unroll
        for (int l = 0; l < 32; ++l) h += (float)((ml_lo >> l) & 1u) * wLp[l];
#pragma unroll
        for (int l = 32; l < NLN; ++l) h += (float)((ml_hi >> (l - 32)) & 1u) * wLp[l];

        bool sp = false;
        if (lane < NPN) {
            v_pn = ALPHA * v_pn + apn - h;
            sp = (v_pn - VTH) > 0.f;
            if (sp) v_pn = 0.f;
        }
        const unsigned long long mPn = __ballot(sp);
        if (lane == 0) outm[t] = mPn;
        ab = abn;
    }
}

// ===================== Phase 2: KC two-compartment + APL + logits =====================
// (R5 version, proven 90 us / absmax 0.0 — unchanged)
__global__ __launch_bounds__(TPB)
void phase2_kernel(const unsigned long long* __restrict__ g_masks, // [B,20]
                   const float* __restrict__ pn_to_kc,  // [42,2000]
                   const float* __restrict__ kc_to_apl, // [2000,1]
                   const float* __restrict__ apl_to_kc, // [1,2000]
                   const float* __restrict__ dec_w,     // [2000,34]
                   const float* __restrict__ dec_b,     // [34]
                   float* __restrict__ out)             // [B,34]
{
    __shared__ float sRed[2][4];
    __shared__ float sRed2[4 * NOD];

    const int tid  = threadIdx.x;
    const int lane = tid & 63;
    const int wid  = tid >> 6;
    const int b    = blockIdx.x;

    const int  kbase = tid * KPER;
    const bool act   = (kbase < NKC);   // tid < 250
    float vd[KPER], va[KPER], cnt[KPER], wa2k[KPER], wk2a[KPER];
#pragma unroll
    for (int j = 0; j < KPER; ++j) { vd[j] = 0.f; va[j] = 0.f; cnt[j] = 0.f; }
    {
        const float4* a4 = (const float4*)(apl_to_kc + (act ? kbase : 0));
        const float4* k4 = (const float4*)(kc_to_apl + (act ? kbase : 0));
        float4 a0 = a4[0], a1 = a4[1], k0 = k4[0], k1 = k4[1];
        const float g = act ? 1.f : 0.f;
        wa2k[0] = g * a0.x; wa2k[1] = g * a0.y; wa2k[2] = g * a0.z; wa2k[3] = g * a0.w;
        wa2k[4] = g * a1.x; wa2k[5] = g * a1.y; wa2k[6] = g * a1.z; wa2k[7] = g * a1.w;
        wk2a[0] = g * k0.x; wk2a[1] = g * k0.y; wk2a[2] = g * k0.z; wk2a[3] = g * k0.w;
        wk2a[4] = g * k1.x; wk2a[5] = g * k1.y; wk2a[6] = g * k1.z; wk2a[7] = g * k1.w;
    }
    if (tid < 8) sRed[tid >> 2][tid & 3] = 0.f;   // zero both buffers
    __syncthreads();

    const unsigned long long* gm = g_masks + (long)b * NSTEPS;

    for (int t = 0; t < NSTEPS; ++t) {
        const float* rp = sRed[(t + 1) & 1];
        const float apl = fmaxf(rp[0] + rp[1] + rp[2] + rp[3], 0.f);

#pragma unroll
        for (int j = 0; j < KPER; ++j) vd[j] = ALPHA * vd[j] - apl * wa2k[j];

        unsigned long long m = gm[t];   // wave-uniform scalar load
        while (m) {
            const int p0 = __builtin_ctzll(m); m &= m - 1;
            int p1 = p0; float f1 = 0.f;
            if (m) { p1 = __builtin_ctzll(m); m &= m - 1; f1 = 1.f; }
            if (act) {
                const float4* w0 = (const float4*)(pn_to_kc + (long)p0 * NKC + kbase);
                const float4* w1 = (const float4*)(pn_to_kc + (long)p1 * NKC + kbase);
                float4 a0 = w0[0], a1 = w0[1];
                float4 b0 = w1[0], b1 = w1[1];
                vd[0] += a0.x; vd[1] += a0.y; vd[2] += a0.z; vd[3] += a0.w;
                vd[4] += a1.x; vd[5] += a1.y; vd[6] += a1.z; vd[7] += a1.w;
                vd[0] += f1 * b0.x; vd[1] += f1 * b0.y; vd[2] += f1 * b0.z; vd[3] += f1 * b0.w;
                vd[4] += f1 * b1.x; vd[5] += f1 * b1.y; vd[6] += f1 * b1.z; vd[7] += f1 * b1.w;
            }
        }

        float aplp = 0.f;
#pragma unroll
        for (int j = 0; j < KPER; ++j) {
            va[j] = ALPHA * va[j] + GSOMA * (vd[j] - va[j]);
            float s = (va[j] - VTH) > 0.f ? 1.f : 0.f;
            va[j] *= (1.f - s);
            cnt[j] += s;
            aplp += s * wk2a[j];
        }
        for (int off = 32; off > 0; off >>= 1) aplp += __shfl_xor(aplp, off, 64);
        if (lane == 0) sRed[t & 1][wid] = aplp;
        __syncthreads();
    }

    float acc[NOD];
#pragma unroll
    for (int o = 0; o < NOD; ++o) acc[o] = 0.f;
    if (act) {
#pragma unroll
        for (int j = 0; j < KPER; ++j) {
            float r = cnt[j] / 20.0f;
            if (r != 0.f) {
                const float* wr = dec_w + (long)(kbase + j) * NOD;
#pragma unroll
                for (int o = 0; o < NOD; ++o) acc[o] += r * wr[o];
            }
        }
    }
#pragma unroll
    for (int o = 0; o < NOD; ++o) {
        float v = acc[o];
        for (int off = 32; off > 0; off >>= 1) v += __shfl_xor(v, off, 64);
        if (lane == 0) sRed2[wid * NOD + o] = v;
    }
    __syncthreads();
    if (tid < NOD) {
        float v = sRed2[tid] + sRed2[NOD + tid] + sRed2[2 * NOD + tid] +
                  sRed2[3 * NOD + tid] + dec_b[tid];
        out[(long)b * NOD + tid] = v;
    }
}

// ========== Mid fallback: R5's proven ctz phase1 (ws in [655KB, 1.97MB)) ==========
__global__ __launch_bounds__(TPB)
void phase1_ctz(const float* __restrict__ or_input, const float* __restrict__ or_gains,
                const float* __restrict__ mapping, const float* __restrict__ orn_to_pn,
                const float* __restrict__ orn_to_ln, const float* __restrict__ ln_to_pn,
                unsigned long long* __restrict__ g_masks, int batch)
{
    __shared__ float sW_ol[NORN * NLN + 24];
    __shared__ float sW_op[NORN * NPN + 24];
    __shared__ float sW_lp[NLN * NPN + 24];
    __shared__ float sSpg[NOR];

    const int tid  = threadIdx.x;
    const int lane = tid & 63;
    const int wid  = tid >> 6;

    for (int i = tid; i < NORN * NLN; i += TPB) sW_ol[i] = orn_to_ln[i];
    for (int i = tid; i < NORN * NPN; i += TPB) sW_op[i] = orn_to_pn[i];
    for (int i = tid; i < NLN * NPN;  i += TPB) sW_lp[i] = ln_to_pn[i];
    if (tid < NOR) sSpg[tid] = log1pf(expf(or_gains[tid]));
    __syncthreads();

    const int row = blockIdx.x * 4 + wid;
    if (row >= batch) return;

    float drive = 0.f;
    if (lane < NORN) {
        const float* x = or_input + (long)row * NOR;
        for (int i = 0; i < NOR; ++i) drive += x[i] * sSpg[i] * mapping[i * NORN + lane];
        drive *= ISCALE;
    }

    float v_orn = 0.f, v_ln = 0.f, v_pn = 0.f;
    unsigned long long* outm = g_masks + (long)row * NSTEPS;

    for (int t = 0; t < NSTEPS; ++t) {
        bool so = false;
        if (lane < NORN) {
            v_orn = ALPHA * v_orn + drive;
            so = (v_orn - VTH) > 0.f;
            if (so) v_orn = 0.f;
        }
        const unsigned long long mOrn = __ballot(so);

        float aln = 0.f, apn = 0.f;
        {
            unsigned long long m = mOrn;
            while (m) {
                int o0 = __builtin_ctzll(m); m &= m - 1;
                int o1 = o0, o2 = o0, o3 = o0;
                float f1 = 0.f, f2 = 0.f, f3 = 0.f;
                if (m) { o1 = __builtin_ctzll(m); m &= m - 1; f1 = 1.f; }
                if (m) { o2 = __builtin_ctzll(m); m &= m - 1; f2 = 1.f; }
                if (m) { o3 = __builtin_ctzll(m); m &= m - 1; f3 = 1.f; }
                float l0 = sW_ol[o0 * NLN + lane];
                float l1 = sW_ol[o1 * NLN + lane];
                float l2 = sW_ol[o2 * NLN + lane];
                float l3 = sW_ol[o3 * NLN + lane];
                float p0 = sW_op[o0 * NPN + lane];
                float p1 = sW_op[o1 * NPN + lane];
                float p2 = sW_op[o2 * NPN + lane];
                float p3 = sW_op[o3 * NPN + lane];
                aln += l0; aln += f1 * l1; aln += f2 * l2; aln += f3 * l3;
                apn += p0; apn += f1 * p1; apn += f2 * p2; apn += f3 * p3;
            }
        }

        bool sl = false;
        if (lane < NLN) {
            v_ln = ALPHA * v_ln + aln;
            sl = (v_ln - VTH) > 0.f;
            if (sl) v_ln = 0.f;
        }
        const unsigned long long mLn = __ballot(sl);

        float h = 0.f;
        {
            unsigned long long m = mLn;
            while (m) {
                int l0i = __builtin_ctzll(m); m &= m - 1;
                int l1i = l0i, l2i = l0i, l3i = l0i;
                float f1 = 0.f, f2 = 0.f, f3 = 0.f;
                if (m) { l1i = __builtin_ctzll(m); m &= m - 1; f1 = 1.f; }
                if (m) { l2i = __builtin_ctzll(m); m &= m - 1; f2 = 1.f; }
                if (m) { l3i = __builtin_ctzll(m); m &= m - 1; f3 = 1.f; }
                float w0 = sW_lp[l0i * NPN + lane];
                float w1 = sW_lp[l1i * NPN + lane];
                float w2 = sW_lp[l2i * NPN + lane];
                float w3 = sW_lp[l3i * NPN + lane];
                h += w0; h += f1 * w1; h += f2 * w2; h += f3 * w3;
            }
        }

        bool sp = false;
        if (lane < NPN) {
            v_pn = ALPHA * v_pn + apn - h;
            sp = (v_pn - VTH) > 0.f;
            if (sp) v_pn = 0.f;
        }
        const unsigned long long mPn = __ballot(sp);
        if (lane == 0) outm[t] = mPn;
    }
}

// ===================== Last fallback: round-1 fused kernel (proven) =====================
__global__ __launch_bounds__(TPB)
void snn_fused(const float* __restrict__ or_input, const float* __restrict__ or_gains,
               const float* __restrict__ mapping, const float* __restrict__ orn_to_pn,
               const float* __restrict__ orn_to_ln, const float* __restrict__ ln_to_pn,
               const float* __restrict__ pn_to_kc, const float* __restrict__ kc_to_apl,
               const float* __restrict__ apl_to_kc, const float* __restrict__ dec_w,
               const float* __restrict__ dec_b, float* __restrict__ out)
{
    __shared__ float sW_ol[NORN * NLN];
    __shared__ float sW_op[NORN * NPN];
    __shared__ float sW_lp[NLN * NPN];
    __shared__ float sDrive[NORN];
    __shared__ float sSpg[NOR];
    __shared__ float sOrn[NORN];
    __shared__ float sLn[NLN];
    __shared__ float sApl;
    __shared__ float sRed[4];
    __shared__ float sRed2[4 * NOD];
    __shared__ unsigned long long sMask;

    const int tid = threadIdx.x;
    const int b   = blockIdx.x;

    for (int i = tid; i < NORN * NLN; i += TPB) sW_ol[i] = orn_to_ln[i];
    for (int i = tid; i < NORN * NPN; i += TPB) sW_op[i] = orn_to_pn[i];
    for (int i = tid; i < NLN * NPN;  i += TPB) sW_lp[i] = ln_to_pn[i];
    if (tid < NOR) sSpg[tid] = log1pf(expf(or_gains[tid]));
    if (tid == 0)  sApl = 0.f;
    __syncthreads();

    if (tid < NORN) {
        const float* x = or_input + (long)b * NOR;
        float d = 0.f;
        for (int i = 0; i < NOR; ++i) d += x[i] * sSpg[i] * mapping[i * NORN + tid];
        sDrive[tid] = d * ISCALE;
    }

    const int  kbase = tid * KPER;
    const bool act   = (kbase < NKC);
    float vd[KPER], va[KPER], cnt[KPER], wa2k[KPER], wk2a[KPER];
#pragma unroll
    for (int j = 0; j < KPER; ++j) {
        vd[j] = 0.f; va[j] = 0.f; cnt[j] = 0.f;
        wa2k[j] = act ? apl_to_kc[kbase + j] : 0.f;
        wk2a[j] = act ? kc_to_apl[kbase + j] : 0.f;
    }
    float v_orn = 0.f, v_ln = 0.f, v_pn = 0.f, v_pn_exc = 0.f;
    __syncthreads();

    for (int t = 0; t < NSTEPS; ++t) {
        if (tid < NORN) {
            v_orn = ALPHA * v_orn + sDrive[tid];
            float s = (v_orn - VTH) > 0.f ? 1.f : 0.f;
            v_orn *= (1.f - s);
            sOrn[tid] = s;
        }
        __syncthreads();
        if (tid < NLN) {
            float a = 0.f;
            for (int o = 0; o < NORN; ++o) a += sOrn[o] * sW_ol[o * NLN + tid];
            v_ln = ALPHA * v_ln + a;
            float s = (v_ln - VTH) > 0.f ? 1.f : 0.f;
            v_ln *= (1.f - s);
            sLn[tid] = s;
        } else if (tid >= 64 && tid < 64 + NPN) {
            const int j = tid - 64;
            float a = 0.f;
            for (int o = 0; o < NORN; ++o) a += sOrn[o] * sW_op[o * NPN + j];
            v_pn_exc = a;
        }
        __syncthreads();
        if (tid >= 64 && tid < 64 + NPN) {
            const int j = tid - 64;
            float inh = 0.f;
            for (int l = 0; l < NLN; ++l) inh += sLn[l] * sW_lp[l * NPN + j];
            v_pn = ALPHA * v_pn + v_pn_exc - inh;
            bool s = (v_pn - VTH) > 0.f;
            if (s) v_pn = 0.f;
            unsigned long long bal = __ballot(s);
            if (tid == 64) sMask = bal;
        }
        __syncthreads();
        {
            const float apl = sApl;
#pragma unroll
            for (int j = 0; j < KPER; ++j) vd[j] = ALPHA * vd[j] - apl * wa2k[j];
            unsigned long long m = sMask;
            while (m) {
                const int p = __builtin_ctzll(m);
                m &= m - 1;
                if (act) {
                    const float4* w = (const float4*)(pn_to_kc + (long)p * NKC + kbase);
                    float4 w0 = w[0], w1 = w[1];
                    vd[0] += w0.x; vd[1] += w0.y; vd[2] += w0.z; vd[3] += w0.w;
                    vd[4] += w1.x; vd[5] += w1.y; vd[6] += w1.z; vd[7] += w1.w;
                }
            }
            float aplp = 0.f;
#pragma unroll
            for (int j = 0; j < KPER; ++j) {
                va[j] = ALPHA * va[j] + GSOMA * (vd[j] - va[j]);
                float s = (va[j] - VTH) > 0.f ? 1.f : 0.f;
                va[j] *= (1.f - s);
                cnt[j] += s;
                aplp += s * wk2a[j];
            }
            for (int off = 32; off > 0; off >>= 1) aplp += __shfl_xor(aplp, off, 64);
            if ((tid & 63) == 0) sRed[tid >> 6] = aplp;
        }
        __syncthreads();
        if (tid == 0) {
            float a = sRed[0] + sRed[1] + sRed[2] + sRed[3];
            sApl = fmaxf(a, 0.f);
        }
    }

    float acc[NOD];
#pragma unroll
    for (int o = 0; o < NOD; ++o) acc[o] = 0.f;
    if (act) {
#pragma unroll
        for (int j = 0; j < KPER; ++j) {
            float r = cnt[j] / 20.0f;
            if (r != 0.f) {
                const float* wr = dec_w + (long)(kbase + j) * NOD;
#pragma unroll
                for (int o = 0; o < NOD; ++o) acc[o] += r * wr[o];
            }
        }
    }
#pragma unroll
    for (int o = 0; o < NOD; ++o) {
        float v = acc[o];
        for (int off = 32; off > 0; off >>= 1) v += __shfl_xor(v, off, 64);
        if ((tid & 63) == 0) sRed2[(tid >> 6) * NOD + o] = v;
    }
    __syncthreads();
    if (tid < NOD) {
        float v = sRed2[tid] + sRed2[NOD + tid] + sRed2[2 * NOD + tid] +
                  sRed2[3 * NOD + tid] + dec_b[tid];
        out[(long)b * NOD + tid] = v;
    }
}

extern "C" void kernel_launch(void* const* d_in, const int* in_sizes, int n_in,
                              void* d_out, int out_size, void* d_ws, size_t ws_size,
                              hipStream_t stream) {
    (void)n_in; (void)out_size;
    const float* or_input  = (const float*)d_in[0];
    const float* or_gains  = (const float*)d_in[1];
    const float* mapping   = (const float*)d_in[2];
    const float* orn_to_pn = (const float*)d_in[3];
    const float* orn_to_ln = (const float*)d_in[4];
    const float* ln_to_pn  = (const float*)d_in[5];
    const float* pn_to_kc  = (const float*)d_in[6];
    const float* kc_to_apl = (const float*)d_in[7];
    const float* apl_to_kc = (const float*)d_in[8];
    const float* dec_w     = (const float*)d_in[9];
    const float* dec_b     = (const float*)d_in[10];
    float* out = (float*)d_out;

    const int batch = in_sizes[0] / NOR;  // 4096
    const size_t needAB = (size_t)batch * NSTEPS * sizeof(ulonglong2);          // 1.31 MB
    const size_t needPN = (size_t)batch * NSTEPS * sizeof(unsigned long long);  // 0.66 MB

    if (ws_size >= needAB + needPN) {
        ulonglong2* gAB = (ulonglong2*)d_ws;
        unsigned long long* gPN = (unsigned long long*)((char*)d_ws + needAB);
        hipLaunchKernelGGL(phase1a, dim3(batch), dim3(64), 0, stream,
                           or_input, or_gains, mapping, orn_to_ln, gAB, batch);
        hipLaunchKernelGGL(phase1b, dim3(batch), dim3(64), 0, stream,
                           orn_to_pn, ln_to_pn, gAB, gPN, batch);
        hipLaunchKernelGGL(phase2_kernel, dim3(batch), dim3(TPB), 0, stream,
                           gPN, pn_to_kc, kc_to_apl, apl_to_kc, dec_w, dec_b, out);
    } else if (ws_size >= needPN) {
        unsigned long long* gPN = (unsigned long long*)d_ws;
        hipLaunchKernelGGL(phase1_ctz, dim3((batch + 3) / 4), dim3(TPB), 0, stream,
                           or_input, or_gains, mapping, orn_to_pn, orn_to_ln, ln_to_pn,
                           gPN, batch);
        hipLaunchKernelGGL(phase2_kernel, dim3(batch), dim3(TPB), 0, stream,
                           gPN, pn_to_kc, kc_to_apl, apl_to_kc, dec_w, dec_b, out);
    } else {
        hipLaunchKernelGGL(snn_fused, dim3(batch), dim3(TPB), 0, stream,
                           or_input, or_gains, mapping, orn_to_pn, orn_to_ln,
                           ln_to_pn, pn_to_kc, kc_to_apl, apl_to_kc, dec_w, dec_b, out);
    }
}